// Round 2
// baseline (785.259 us; speedup 1.0000x reference)
//
#include <hip/hip_runtime.h>
#include <hip/hip_bf16.h>

// ---------------------------------------------------------------------------
// GlobalSAModule: h = MLP3(cat(x,pos)); pooled = segment_max(h);
//                 out = cat(pooled[batch_skip], x_skip)
// Strategy: split-bf16 (hi+lo) MFMA GEMMs (3 products ~= fp32 accuracy),
// layer3 fused with segment-max (h3 [N,1024] never materialized),
// then gather+concat (knn_interpolate with 1 source/graph == gather).
// ---------------------------------------------------------------------------

typedef __attribute__((ext_vector_type(8))) short bf16x8;
typedef __attribute__((ext_vector_type(4))) float f32x4;

#define GLD_LDS16(src, dst) __builtin_amdgcn_global_load_lds( \
    (const __attribute__((address_space(1))) unsigned int*)(src), \
    (__attribute__((address_space(3))) unsigned int*)(dst), 16, 0, 0)

__device__ __forceinline__ unsigned short f2bf(float f) {
  unsigned int u = __float_as_uint(f);
  unsigned int r = (u + 0x7FFFu + ((u >> 16) & 1u)) >> 16;   // RNE
  return (unsigned short)r;
}
__device__ __forceinline__ float bf2f(unsigned short h) {
  return __uint_as_float(((unsigned int)h) << 16);
}

// --- pack cat(x,pos) -> [N][320] hi/lo bf16 planes (zero-padded K) ----------
__global__ void pack_a1(const float* __restrict__ x, const float* __restrict__ pos,
                        unsigned short* __restrict__ ah, unsigned short* __restrict__ al) {
  const int n = blockIdx.x;
  const int c = threadIdx.x;                       // 0..319 (5 waves)
  float v = 0.f;
  if (c < 256)      v = x[(size_t)n * 256 + c];
  else if (c < 259) v = pos[(size_t)n * 3 + (c - 256)];
  unsigned short hi = f2bf(v);
  ah[(size_t)n * 320 + c] = hi;
  al[(size_t)n * 320 + c] = f2bf(v - bf2f(hi));
}

// --- pack+transpose weights: W[K][Nout] fp32 -> Wt[Nout][KP] hi/lo ----------
__global__ void pack_w(const float* __restrict__ w, unsigned short* __restrict__ wh,
                       unsigned short* __restrict__ wl, int K, int Nout) {
  const int no = blockIdx.x;
  const int k = threadIdx.x;
  const int KP = blockDim.x;                        // padded K
  float v = (k < K) ? w[(size_t)k * Nout + no] : 0.f;
  unsigned short hi = f2bf(v);
  wh[(size_t)no * KP + k] = hi;
  wl[(size_t)no * KP + k] = f2bf(v - bf2f(hi));
}

__global__ void zero_pool(unsigned int* __restrict__ p) {
  p[blockIdx.x * 1024 + threadIdx.x] = 0u;          // 0.0f bits; relu outputs >= 0
}

// --- split-bf16 GEMM: C = relu(A @ Wt^T + b) --------------------------------
// A planes [M][KP], B planes (pre-transposed) [NOUT][KP].
// MODE 0: write C as hi/lo bf16 planes [M][NOUT]
// MODE 1: fused column-max per 128-row graph-aligned tile -> atomicMax(pooled)
// LDS k-chunk placement XOR-swizzled via pre-swizzled GLOBAL source (rule #21:
// linear gload_lds dest + involution applied on both source addr and ds_read).
template<int KP, int NOUT, int MODE>
__global__ __launch_bounds__(256, 2)
void gemm_split(const unsigned short* __restrict__ gAh, const unsigned short* __restrict__ gAl,
                const unsigned short* __restrict__ gBh, const unsigned short* __restrict__ gBl,
                const float* __restrict__ bias,
                unsigned short* __restrict__ Ch, unsigned short* __restrict__ Cl,
                unsigned int* __restrict__ pooled, const int* __restrict__ batch) {
  constexpr int BM = 128, BN = 128, BK = 64;
  constexpr int NB = NOUT / BN;
  __shared__ unsigned short lds[4 * BM * BK];       // Ah,Al,Bh,Bl tiles: 64 KiB

  // T1: bijective XCD swizzle (gridDim.x % 8 == 0 for all instantiations).
  const int nwg = gridDim.x;
  const int bid = (blockIdx.x % 8) * (nwg / 8) + blockIdx.x / 8;
  const int bm = bid / NB, bn = bid % NB;
  const int r0 = bm * BM, c0 = bn * BN;
  const int tid = threadIdx.x;
  const int lane = tid & 63, wid = tid >> 6;        // 4 waves
  const int wm = wid >> 1, wc = wid & 1;            // wave -> 64x64 C sub-tile
  const int al15 = lane & 15, l4 = lane >> 4;
  const int swz = lane & 7, lr = lane >> 3;

  f32x4 acc[4][4] = {};                             // 64 fp32 accum / lane

  // Each wave stages one 16 KiB plane (A_hi/A_lo/B_hi/B_lo).
  const unsigned short* plane = (wid == 0) ? gAh : (wid == 1) ? gAl : (wid == 2) ? gBh : gBl;
  const int rb = (wid < 2) ? r0 : c0;
  unsigned short* sbase = lds + wid * (BM * BK);
  // global row = rb + lr + 8t ; k-chunk = (lane&7) ^ (row&7) = swz ^ lr
  const unsigned short* gsrc0 = plane + (size_t)(rb + lr) * KP + ((swz ^ lr) << 3);
  unsigned short* ldst0 = sbase + lane * 8;         // linear dest: lane*16B

  for (int kt = 0; kt < KP / BK; ++kt) {
    {
      const unsigned short* s = gsrc0 + kt * BK;
      unsigned short* d = ldst0;
      #pragma unroll
      for (int t = 0; t < 16; ++t) {                // 16 x 1 KiB per wave
        GLD_LDS16(s, d);
        s += 8 * KP;
        d += 512;
      }
    }
    __syncthreads();

    const unsigned short* sA_h = lds;
    const unsigned short* sA_l = lds + BM * BK;
    const unsigned short* sB_h = lds + 2 * BM * BK;
    const unsigned short* sB_l = lds + 3 * BM * BK;

    #pragma unroll
    for (int ks = 0; ks < BK / 32; ++ks) {
      bf16x8 fah[4], fal[4], fbh[4], fbl[4];
      const int kc = ks * 4 + l4;                   // global 16B k-chunk index
      #pragma unroll
      for (int i = 0; i < 4; ++i) {
        const int arow = wm * 64 + i * 16 + al15;   // arow&7 == swz
        const int aoff = arow * BK + ((kc ^ swz) << 3);
        fah[i] = *(const bf16x8*)(sA_h + aoff);
        fal[i] = *(const bf16x8*)(sA_l + aoff);
        const int brow = wc * 64 + i * 16 + al15;
        const int boff = brow * BK + ((kc ^ swz) << 3);
        fbh[i] = *(const bf16x8*)(sB_h + boff);
        fbl[i] = *(const bf16x8*)(sB_l + boff);
      }
      #pragma unroll
      for (int i = 0; i < 4; ++i)
        #pragma unroll
        for (int j = 0; j < 4; ++j) {
          acc[i][j] = __builtin_amdgcn_mfma_f32_16x16x32_bf16(fah[i], fbh[j], acc[i][j], 0, 0, 0);
          acc[i][j] = __builtin_amdgcn_mfma_f32_16x16x32_bf16(fah[i], fbl[j], acc[i][j], 0, 0, 0);
          acc[i][j] = __builtin_amdgcn_mfma_f32_16x16x32_bf16(fal[i], fbh[j], acc[i][j], 0, 0, 0);
        }
    }
    __syncthreads();
  }

  if (MODE == 0) {
    // C/D layout (m89-verified): col = lane&15, row = (lane>>4)*4 + reg
    #pragma unroll
    for (int j = 0; j < 4; ++j) {
      const int col = c0 + wc * 64 + j * 16 + al15;
      const float bz = bias[col];
      #pragma unroll
      for (int i = 0; i < 4; ++i) {
        const int row0 = r0 + wm * 64 + i * 16 + l4 * 4;
        #pragma unroll
        for (int r = 0; r < 4; ++r) {
          float v = fmaxf(acc[i][j][r] + bz, 0.f);
          unsigned short hi = f2bf(v);
          Ch[(size_t)(row0 + r) * NOUT + col] = hi;
          Cl[(size_t)(row0 + r) * NOUT + col] = f2bf(v - bf2f(hi));
        }
      }
    }
  } else {
    // fused segment-max: a 128-row tile never straddles graphs (4096%128==0)
    const int g = batch[r0];
    float* pb = (float*)lds;                        // LDS reuse after final barrier
    #pragma unroll
    for (int j = 0; j < 4; ++j) {
      const int col128 = wc * 64 + j * 16 + al15;
      const float bz = bias[c0 + col128];
      float cm = 0.f;                               // relu floor
      #pragma unroll
      for (int i = 0; i < 4; ++i)
        #pragma unroll
        for (int r = 0; r < 4; ++r)
          cm = fmaxf(cm, acc[i][j][r] + bz);
      cm = fmaxf(cm, __shfl_xor(cm, 16));           // reduce over l4 (rows)
      cm = fmaxf(cm, __shfl_xor(cm, 32));
      if (l4 == 0) pb[wm * 128 + col128] = cm;
    }
    __syncthreads();
    if (tid < 128) {
      float m = fmaxf(pb[tid], pb[128 + tid]);
      // relu outputs non-negative: uint bit compare == float compare
      atomicMax(pooled + (size_t)g * 1024 + c0 + tid, __float_as_uint(m));
    }
  }
}

// --- out[n] = cat(pooled[batch_skip[n]], x_skip[n]) -------------------------
__global__ void write_out(const float* __restrict__ pooled, const float* __restrict__ x_skip,
                          const int* __restrict__ batch_skip, float* __restrict__ out,
                          int N) {
  const int t = threadIdx.x;                        // 256
  for (int n = blockIdx.x; n < N; n += gridDim.x) {
    const int g = batch_skip[n];
    const float4* ps = (const float4*)(pooled + (size_t)g * 1024);
    float4* o = (float4*)(out + (size_t)n * 1280);
    o[t] = ps[t];                                   // 1024 floats (L1/L2-hot)
    if (t < 64) {
      const float4* xs = (const float4*)(x_skip + (size_t)n * 256);
      o[256 + t] = xs[t];                           // 256 floats
    }
  }
}

extern "C" void kernel_launch(void* const* d_in, const int* in_sizes, int n_in,
                              void* d_out, int out_size, void* d_ws, size_t ws_size,
                              hipStream_t stream) {
  const float* x        = (const float*)d_in[0];
  const float* pos      = (const float*)d_in[1];
  const int*   batch    = (const int*)d_in[2];
  const float* x_skip   = (const float*)d_in[3];
  const int*   batch_sk = (const int*)d_in[5];
  const float* W1 = (const float*)d_in[6];
  const float* b1 = (const float*)d_in[7];
  const float* W2 = (const float*)d_in[8];
  const float* b2 = (const float*)d_in[9];
  const float* W3 = (const float*)d_in[10];
  const float* b3 = (const float*)d_in[11];
  float* out = (float*)d_out;

  // workspace layout (195 MB peak, disjoint-lifetime aliasing):
  //   h2h [0,64M) h2l [64M,128M)  -- GEMM2 out / GEMM3 in
  //   a1h [0,40M) a1l [40M,80M)   -- pack out / GEMM1 in (dead before h2 written)
  //   h1h [128M,160M) h1l [160M,192M) -- GEMM1 out / GEMM2 in
  //   weights + pooled at [192M, ...)
  char* ws = (char*)d_ws;
  unsigned short* a1h = (unsigned short*)(ws);
  unsigned short* a1l = (unsigned short*)(ws + 41943040);
  unsigned short* h2h = (unsigned short*)(ws);
  unsigned short* h2l = (unsigned short*)(ws + 67108864);
  size_t off = 134217728;
  unsigned short* h1h = (unsigned short*)(ws + off); off += 33554432;
  unsigned short* h1l = (unsigned short*)(ws + off); off += 33554432;
  unsigned short* w1h = (unsigned short*)(ws + off); off += 163840;
  unsigned short* w1l = (unsigned short*)(ws + off); off += 163840;
  unsigned short* w2h = (unsigned short*)(ws + off); off += 262144;
  unsigned short* w2l = (unsigned short*)(ws + off); off += 262144;
  unsigned short* w3h = (unsigned short*)(ws + off); off += 1048576;
  unsigned short* w3l = (unsigned short*)(ws + off); off += 1048576;
  unsigned int*  pooled = (unsigned int*)(ws + off);             // 16*1024*4

  hipLaunchKernelGGL(pack_w, dim3(256),  dim3(320), 0, stream, W1, w1h, w1l, 259, 256);
  hipLaunchKernelGGL(pack_w, dim3(512),  dim3(256), 0, stream, W2, w2h, w2l, 256, 512);
  hipLaunchKernelGGL(pack_w, dim3(1024), dim3(512), 0, stream, W3, w3h, w3l, 512, 1024);
  hipLaunchKernelGGL(pack_a1, dim3(65536), dim3(320), 0, stream, x, pos, a1h, a1l);
  hipLaunchKernelGGL(zero_pool, dim3(16), dim3(1024), 0, stream, pooled);

  hipLaunchKernelGGL((gemm_split<320, 256, 0>), dim3(512 * 2), dim3(256), 0, stream,
                     a1h, a1l, w1h, w1l, b1, h1h, h1l,
                     (unsigned int*)nullptr, (const int*)nullptr);
  hipLaunchKernelGGL((gemm_split<256, 512, 0>), dim3(512 * 4), dim3(256), 0, stream,
                     h1h, h1l, w2h, w2l, b2, h2h, h2l,
                     (unsigned int*)nullptr, (const int*)nullptr);
  hipLaunchKernelGGL((gemm_split<512, 1024, 1>), dim3(512 * 8), dim3(256), 0, stream,
                     h2h, h2l, w3h, w3l, b3,
                     (unsigned short*)nullptr, (unsigned short*)nullptr, pooled, batch);

  hipLaunchKernelGGL(write_out, dim3(2048), dim3(256), 0, stream,
                     (const float*)pooled, x_skip, batch_sk, out, 65536);
}

// Round 3
// 771.096 us; speedup vs baseline: 1.0184x; 1.0184x over previous
//
#include <hip/hip_runtime.h>
#include <hip/hip_bf16.h>

// ---------------------------------------------------------------------------
// GlobalSAModule: h = MLP3(cat(x,pos)); pooled = segment_max(h);
//                 out = cat(pooled[batch_skip], x_skip)
// Split-bf16 (hi+lo) MFMA GEMMs, 3 products ~= fp32 accuracy (absmax 5e-4
// verified round 2). Layer3 fused with segment-max. 32x32x16 MFMA path.
// ---------------------------------------------------------------------------

typedef __attribute__((ext_vector_type(8))) short bf16x8;
typedef __attribute__((ext_vector_type(16))) float f32x16;

#define GLD_LDS16(src, dst) __builtin_amdgcn_global_load_lds( \
    (const __attribute__((address_space(1))) unsigned int*)(src), \
    (__attribute__((address_space(3))) unsigned int*)(dst), 16, 0, 0)

__device__ __forceinline__ unsigned short f2bf(float f) {
  unsigned int u = __float_as_uint(f);
  unsigned int r = (u + 0x7FFFu + ((u >> 16) & 1u)) >> 16;   // RNE
  return (unsigned short)r;
}
__device__ __forceinline__ float bf2f(unsigned short h) {
  return __uint_as_float(((unsigned int)h) << 16);
}

// --- pack cat(x,pos) -> [N][320] hi/lo bf16 planes (vectorized) -------------
__global__ void pack_a1(const float* __restrict__ x, const float* __restrict__ pos,
                        unsigned short* __restrict__ ah, unsigned short* __restrict__ al) {
  const int total = 65536 * 80;                    // 80 quads per row of 320
  for (int idx = blockIdx.x * blockDim.x + threadIdx.x; idx < total;
       idx += gridDim.x * blockDim.x) {
    const int n = idx / 80;
    const int q = idx - n * 80;
    float4 v;
    if (q < 64) {
      v = ((const float4*)x)[(size_t)n * 64 + q];
    } else if (q == 64) {
      v.x = pos[(size_t)n * 3 + 0];
      v.y = pos[(size_t)n * 3 + 1];
      v.z = pos[(size_t)n * 3 + 2];
      v.w = 0.f;
    } else {
      v.x = v.y = v.z = v.w = 0.f;
    }
    ushort4 h, l;
    h.x = f2bf(v.x); l.x = f2bf(v.x - bf2f(h.x));
    h.y = f2bf(v.y); l.y = f2bf(v.y - bf2f(h.y));
    h.z = f2bf(v.z); l.z = f2bf(v.z - bf2f(h.z));
    h.w = f2bf(v.w); l.w = f2bf(v.w - bf2f(h.w));
    *(ushort4*)(ah + (size_t)n * 320 + q * 4) = h;
    *(ushort4*)(al + (size_t)n * 320 + q * 4) = l;
  }
}

// --- pack+transpose weights: W[K][Nout] fp32 -> Wt[Nout][KP] hi/lo ----------
__global__ void pack_w(const float* __restrict__ w, unsigned short* __restrict__ wh,
                       unsigned short* __restrict__ wl, int K, int Nout) {
  const int no = blockIdx.x;
  const int k = threadIdx.x;
  const int KP = blockDim.x;                        // padded K
  float v = (k < K) ? w[(size_t)k * Nout + no] : 0.f;
  unsigned short hi = f2bf(v);
  wh[(size_t)no * KP + k] = hi;
  wl[(size_t)no * KP + k] = f2bf(v - bf2f(hi));
}

__global__ void zero_pool(unsigned int* __restrict__ p) {
  p[blockIdx.x * 1024 + threadIdx.x] = 0u;          // 0.0f bits; relu outputs >= 0
}

// --- split-bf16 GEMM: C = relu(A @ Wt^T + b), 32x32x16 MFMA -----------------
// A planes [M][KP], B planes (pre-transposed) [NOUT][KP].
// MODE 0: write C as hi/lo bf16 planes [M][NOUT]
// MODE 1: fused column-max per 128-row graph-aligned tile -> atomicMax(pooled)
// LDS k-chunk XOR-swizzle via pre-swizzled GLOBAL source (rule #21); uniform
// 8-lanes/bank-group on ds_read_b128 (= structural floor, conflict-free).
template<int KP, int NOUT, int MODE>
__global__ __launch_bounds__(256, 2)
void gemm_split(const unsigned short* __restrict__ gAh, const unsigned short* __restrict__ gAl,
                const unsigned short* __restrict__ gBh, const unsigned short* __restrict__ gBl,
                const float* __restrict__ bias,
                unsigned short* __restrict__ Ch, unsigned short* __restrict__ Cl,
                unsigned int* __restrict__ pooled, const int* __restrict__ batch) {
  constexpr int BM = 128, BN = 128, BK = 64;
  constexpr int NB = NOUT / BN;
  __shared__ unsigned short lds[4 * BM * BK];       // Ah,Al,Bh,Bl tiles: 64 KiB

  const int nwg = gridDim.x;                        // % 8 == 0 for all uses
  const int bid = (blockIdx.x % 8) * (nwg / 8) + blockIdx.x / 8;  // XCD swizzle
  const int bm = bid / NB, bn = bid % NB;
  const int r0 = bm * BM, c0 = bn * BN;
  const int tid = threadIdx.x;
  const int lane = tid & 63, wid = tid >> 6;        // 4 waves
  const int wm = wid >> 1, wc = wid & 1;            // wave -> 64x64 C sub-tile
  const int al31 = lane & 31, l5 = lane >> 5;
  const int swz = lane & 7, lr = lane >> 3;

  f32x16 acc[2][2] = {};                            // 64 fp32 accum / lane

  // Each wave stages one 16 KiB plane (A_hi/A_lo/B_hi/B_lo).
  const unsigned short* plane = (wid == 0) ? gAh : (wid == 1) ? gAl : (wid == 2) ? gBh : gBl;
  const int rb = (wid < 2) ? r0 : c0;
  unsigned short* sbase = lds + wid * (BM * BK);
  // global row = rb + lr + 8t ; stored chunk (lane&7) holds logical chunk swz^lr
  const unsigned short* gsrc0 = plane + (size_t)(rb + lr) * KP + ((swz ^ lr) << 3);
  unsigned short* ldst0 = sbase + lane * 8;         // linear dest: lane*16B

  for (int kt = 0; kt < KP / BK; ++kt) {
    {
      const unsigned short* s = gsrc0 + kt * BK;
      unsigned short* d = ldst0;
      #pragma unroll
      for (int t = 0; t < 16; ++t) {                // 16 x 1 KiB per wave
        GLD_LDS16(s, d);
        s += 8 * KP;
        d += 512;
      }
    }
    __syncthreads();

    const unsigned short* sA_h = lds;
    const unsigned short* sA_l = lds + BM * BK;
    const unsigned short* sB_h = lds + 2 * BM * BK;
    const unsigned short* sB_l = lds + 3 * BM * BK;

    #pragma unroll
    for (int ks = 0; ks < BK / 16; ++ks) {
      bf16x8 fah[2], fal[2], fbh[2], fbl[2];
      const int cb = ks * 2 + l5;                   // logical 16B k-chunk
      #pragma unroll
      for (int i = 0; i < 2; ++i) {
        const int arow = wm * 64 + i * 32 + al31;
        const int aoff = arow * BK + ((cb ^ (arow & 7)) << 3);
        fah[i] = *(const bf16x8*)(sA_h + aoff);
        fal[i] = *(const bf16x8*)(sA_l + aoff);
        const int brow = wc * 64 + i * 32 + al31;
        const int boff = brow * BK + ((cb ^ (brow & 7)) << 3);
        fbh[i] = *(const bf16x8*)(sB_h + boff);
        fbl[i] = *(const bf16x8*)(sB_l + boff);
      }
      #pragma unroll
      for (int i = 0; i < 2; ++i)
        #pragma unroll
        for (int j = 0; j < 2; ++j) {
          acc[i][j] = __builtin_amdgcn_mfma_f32_32x32x16_bf16(fah[i], fbh[j], acc[i][j], 0, 0, 0);
          acc[i][j] = __builtin_amdgcn_mfma_f32_32x32x16_bf16(fah[i], fbl[j], acc[i][j], 0, 0, 0);
          acc[i][j] = __builtin_amdgcn_mfma_f32_32x32x16_bf16(fal[i], fbh[j], acc[i][j], 0, 0, 0);
        }
    }
    __syncthreads();
  }

  if (MODE == 0) {
    // C/D 32x32 layout (m74/m101): col=lane&31, row=(reg&3)+8*(reg>>2)+4*(lane>>5)
    #pragma unroll
    for (int i = 0; i < 2; ++i) {
      const int rbase = r0 + wm * 64 + i * 32 + 4 * l5;
      #pragma unroll
      for (int j = 0; j < 2; ++j) {
        const int col = c0 + wc * 64 + j * 32 + al31;
        const float bz = bias[col];
        #pragma unroll
        for (int r = 0; r < 16; ++r) {
          const int row = rbase + (r & 3) + 8 * (r >> 2);
          float v = fmaxf(acc[i][j][r] + bz, 0.f);
          unsigned short hi = f2bf(v);
          Ch[(size_t)row * NOUT + col] = hi;
          Cl[(size_t)row * NOUT + col] = f2bf(v - bf2f(hi));
        }
      }
    }
  } else {
    // fused segment-max: a 128-row tile never straddles graphs (4096%128==0)
    const int g = batch[r0];
    float* pb = (float*)lds;                        // LDS reuse after final barrier
    #pragma unroll
    for (int j = 0; j < 2; ++j) {
      const int colw = wc * 64 + j * 32 + al31;
      const float bz = bias[c0 + colw];
      float cm = 0.f;                               // relu floor
      #pragma unroll
      for (int i = 0; i < 2; ++i)
        #pragma unroll
        for (int r = 0; r < 16; ++r)
          cm = fmaxf(cm, acc[i][j][r] + bz);
      cm = fmaxf(cm, __shfl_xor(cm, 32));           // combine row-halves (l5)
      if (l5 == 0) pb[wm * 128 + colw] = cm;
    }
    __syncthreads();
    if (tid < 128) {
      float m = fmaxf(pb[tid], pb[128 + tid]);
      // relu outputs non-negative: uint bit compare == float compare
      atomicMax(pooled + (size_t)g * 1024 + c0 + tid, __float_as_uint(m));
    }
  }
}

// --- out[n] = cat(pooled[batch_skip[n]], x_skip[n]) -------------------------
__global__ void write_out(const float* __restrict__ pooled, const float* __restrict__ x_skip,
                          const int* __restrict__ batch_skip, float* __restrict__ out,
                          int N) {
  const int t = threadIdx.x;                        // 256
  for (int n = blockIdx.x; n < N; n += gridDim.x) {
    const int g = batch_skip[n];
    const float4* ps = (const float4*)(pooled + (size_t)g * 1024);
    float4* o = (float4*)(out + (size_t)n * 1280);
    o[t] = ps[t];                                   // 1024 floats (L2-hot)
    if (t < 64) {
      const float4* xs = (const float4*)(x_skip + (size_t)n * 256);
      o[256 + t] = xs[t];                           // 256 floats
    }
  }
}

extern "C" void kernel_launch(void* const* d_in, const int* in_sizes, int n_in,
                              void* d_out, int out_size, void* d_ws, size_t ws_size,
                              hipStream_t stream) {
  const float* x        = (const float*)d_in[0];
  const float* pos      = (const float*)d_in[1];
  const int*   batch    = (const int*)d_in[2];
  const float* x_skip   = (const float*)d_in[3];
  const int*   batch_sk = (const int*)d_in[5];
  const float* W1 = (const float*)d_in[6];
  const float* b1 = (const float*)d_in[7];
  const float* W2 = (const float*)d_in[8];
  const float* b2 = (const float*)d_in[9];
  const float* W3 = (const float*)d_in[10];
  const float* b3 = (const float*)d_in[11];
  float* out = (float*)d_out;

  // workspace layout (195 MB peak, disjoint-lifetime aliasing):
  //   h2h [0,64M) h2l [64M,128M)  -- GEMM2 out / GEMM3 in
  //   a1h [0,40M) a1l [40M,80M)   -- pack out / GEMM1 in (dead before h2 written)
  //   h1h [128M,160M) h1l [160M,192M) -- GEMM1 out / GEMM2 in
  char* ws = (char*)d_ws;
  unsigned short* a1h = (unsigned short*)(ws);
  unsigned short* a1l = (unsigned short*)(ws + 41943040);
  unsigned short* h2h = (unsigned short*)(ws);
  unsigned short* h2l = (unsigned short*)(ws + 67108864);
  size_t off = 134217728;
  unsigned short* h1h = (unsigned short*)(ws + off); off += 33554432;
  unsigned short* h1l = (unsigned short*)(ws + off); off += 33554432;
  unsigned short* w1h = (unsigned short*)(ws + off); off += 163840;
  unsigned short* w1l = (unsigned short*)(ws + off); off += 163840;
  unsigned short* w2h = (unsigned short*)(ws + off); off += 262144;
  unsigned short* w2l = (unsigned short*)(ws + off); off += 262144;
  unsigned short* w3h = (unsigned short*)(ws + off); off += 1048576;
  unsigned short* w3l = (unsigned short*)(ws + off); off += 1048576;
  unsigned int*  pooled = (unsigned int*)(ws + off);             // 16*1024*4

  hipLaunchKernelGGL(pack_w, dim3(256),  dim3(320), 0, stream, W1, w1h, w1l, 259, 256);
  hipLaunchKernelGGL(pack_w, dim3(512),  dim3(256), 0, stream, W2, w2h, w2l, 256, 512);
  hipLaunchKernelGGL(pack_w, dim3(1024), dim3(512), 0, stream, W3, w3h, w3l, 512, 1024);
  hipLaunchKernelGGL(pack_a1, dim3(2048), dim3(256), 0, stream, x, pos, a1h, a1l);
  hipLaunchKernelGGL(zero_pool, dim3(16), dim3(1024), 0, stream, pooled);

  hipLaunchKernelGGL((gemm_split<320, 256, 0>), dim3(512 * 2), dim3(256), 0, stream,
                     a1h, a1l, w1h, w1l, b1, h1h, h1l,
                     (unsigned int*)nullptr, (const int*)nullptr);
  hipLaunchKernelGGL((gemm_split<256, 512, 0>), dim3(512 * 4), dim3(256), 0, stream,
                     h1h, h1l, w2h, w2l, b2, h2h, h2l,
                     (unsigned int*)nullptr, (const int*)nullptr);
  hipLaunchKernelGGL((gemm_split<512, 1024, 1>), dim3(512 * 8), dim3(256), 0, stream,
                     h2h, h2l, w3h, w3l, b3,
                     (unsigned short*)nullptr, (unsigned short*)nullptr, pooled, batch);

  hipLaunchKernelGGL(write_out, dim3(4096), dim3(256), 0, stream,
                     (const float*)pooled, x_skip, batch_sk, out, 65536);
}